// Round 3
// baseline (461.848 us; speedup 1.0000x reference)
//
#include <hip/hip_runtime.h>
#include <hip/hip_bf16.h>

// RGCN forward, MI355X. N=100000, E=400000, IN=OUT=256, R=200, B=32.
// Two-phase: (1) relation-sorted tile GEMMs write scaled bf16 messages to a
// msg[E][256] buffer (no atomics); (2) dst-CSR aggregate sums msg rows into
// out (initialized by the self-loop GEMM). Tiered by ws_size with atomic
// fallbacks.

#define NN 100000
#define EE 400000
#define RR 200
#define BB 32
#define MAXTILES 6456   // >= E/64 + R ; divisible by 8 for XCD swizzle
#define SCHUNK 2048
#define NSCAN ((NN + 255) / 256)   // 391

typedef __attribute__((ext_vector_type(8))) short short8v;   // 8 x bf16 (16B)
typedef __attribute__((ext_vector_type(4))) float f32x4;

__device__ __forceinline__ unsigned short f2bf(float f) {
  unsigned u = __float_as_uint(f);
  u += 0x7FFF + ((u >> 16) & 1);          // RNE
  return (unsigned short)(u >> 16);
}
__device__ __forceinline__ float bf2f(unsigned short h) {
  return __uint_as_float(((unsigned)h) << 16);
}

// ---------------------------------------------------------------------------
// Kernel 0: W_pk[r] = bf16(coef[r] @ basis), packed for MFMA B-fragments.
// Layout per relation: [ct=16][kt=8][lane=64][j=8] bf16, where
//   value = W_r[k = kt*32 + (lane>>4)*8 + j][n = ct*16 + (lane&15)].
__global__ __launch_bounds__(256) void k_wgen(const float* __restrict__ basis,
                                              const float* __restrict__ coef,
                                              short* __restrict__ wpk) {
  int t = blockIdx.x * 256 + threadIdx.x;   // 25 * 8192 = 204800 threads
  int rg  = t >> 13;
  int pk8 = t & 8191;
  int lane = pk8 & 63;
  int kt = (pk8 >> 6) & 7;
  int ct = pk8 >> 9;
  int n  = ct * 16 + (lane & 15);
  int k0 = kt * 32 + ((lane >> 4) << 3);
  float acc[8][8];
#pragma unroll
  for (int r = 0; r < 8; ++r)
#pragma unroll
    for (int j = 0; j < 8; ++j) acc[r][j] = 0.f;
  for (int b = 0; b < BB; ++b) {
    float bas[8];
#pragma unroll
    for (int j = 0; j < 8; ++j) bas[j] = basis[b * 65536 + (k0 + j) * 256 + n];
#pragma unroll
    for (int r = 0; r < 8; ++r) {
      float c = coef[(rg * 8 + r) * BB + b];
#pragma unroll
      for (int j = 0; j < 8; ++j) acc[r][j] += c * bas[j];
    }
  }
#pragma unroll
  for (int r = 0; r < 8; ++r) {
    short8v v;
#pragma unroll
    for (int j = 0; j < 8; ++j) v[j] = (short)f2bf(acc[r][j]);
    *(short8v*)(wpk + (size_t)(rg * 8 + r) * 65536 + (size_t)pk8 * 8) = v;
  }
}

// Kernel 0b: pack self_loop_weight [256][256] f32 into same MFMA layout.
__global__ __launch_bounds__(256) void k_slwpk(const float* __restrict__ slw,
                                               short* __restrict__ spk) {
  int t = blockIdx.x * 256 + threadIdx.x;
  int lane = t & 63;
  int kt = (t >> 6) & 7;
  int ct = t >> 9;
  int n  = ct * 16 + (lane & 15);
  int k0 = kt * 32 + ((lane >> 4) << 3);
  short8v v;
#pragma unroll
  for (int j = 0; j < 8; ++j) v[j] = (short)f2bf(slw[(k0 + j) * 256 + n]);
  *(short8v*)(spk + (size_t)t * 8) = v;
}

// Kernel 0c: in_feat f32 -> bf16 once (halves gather bytes; E/N ~ 4x reuse).
__global__ __launch_bounds__(256) void k_feat(const float* __restrict__ in_feat,
                                              unsigned short* __restrict__ featb) {
  const int total = NN * 64;                 // float4 count
  for (int i = blockIdx.x * 256 + threadIdx.x; i < total; i += gridDim.x * 256) {
    float4 v = ((const float4*)in_feat)[i];
    ushort4 h;
    h.x = f2bf(v.x); h.y = f2bf(v.y); h.z = f2bf(v.z); h.w = f2bf(v.w);
    ((ushort4*)featb)[i] = h;
  }
}

// Kernel 1: histogram of etype (LDS-aggregated) + in-degree of dst.
__global__ __launch_bounds__(256) void k_hist(const int* __restrict__ etype,
                                              const int* __restrict__ dst,
                                              int* __restrict__ hist,
                                              int* __restrict__ deg) {
  __shared__ int lh[RR];
  int tid = threadIdx.x;
  for (int i = tid; i < RR; i += 256) lh[i] = 0;
  __syncthreads();
  for (int e = blockIdx.x * 256 + tid; e < EE; e += gridDim.x * 256) {
    atomicAdd(&lh[etype[e]], 1);
    atomicAdd(&deg[dst[e]], 1);
  }
  __syncthreads();
  for (int i = tid; i < RR; i += 256)
    if (lh[i]) atomicAdd(&hist[i], lh[i]);
}

// Kernel 2 (single block): scan 200 etype bins, emit tile descs, init cursors.
__global__ __launch_bounds__(256) void k_scan(const int* __restrict__ hist,
                                              int* __restrict__ cur,
                                              int4* __restrict__ tdesc) {
  __shared__ int h[RR];
  __shared__ int off[RR];
  __shared__ int toff[RR];
  __shared__ int tot;
  int tid = threadIdx.x;
  for (int i = tid; i < RR; i += 256) h[i] = hist[i];
  __syncthreads();
  if (tid == 0) {
    int s = 0, ts = 0;
    for (int r = 0; r < RR; ++r) {
      off[r] = s; s += h[r];
      toff[r] = ts; ts += (h[r] + 63) >> 6;
    }
    tot = ts;
  }
  __syncthreads();
  if (tid < RR) {
    int r = tid, cnt = h[r], base = off[r], to = toff[r];
    cur[r] = base;
    int nt = (cnt + 63) >> 6;
    for (int t2 = 0; t2 < nt; ++t2)
      tdesc[to + t2] = make_int4(r, base + t2 * 64, min(64, cnt - t2 * 64), 0);
  }
  for (int i = tot + tid; i < MAXTILES; i += 256)
    tdesc[i] = make_int4(0, 0, 0, 0);
}

// Kernel 3: scatter edge ids into relation-sorted perm (block-aggregated).
__global__ __launch_bounds__(256) void k_scatter(const int* __restrict__ etype,
                                                 int* __restrict__ cur,
                                                 int* __restrict__ perm) {
  __shared__ int lh[RR];
  __shared__ int lbase[RR];
  __shared__ int lcur[RR];
  int tid = threadIdx.x;
  int e0 = blockIdx.x * SCHUNK;
  for (int i = tid; i < RR; i += 256) lh[i] = 0;
  __syncthreads();
  for (int i = tid; i < SCHUNK; i += 256) {
    int e = e0 + i;
    if (e < EE) atomicAdd(&lh[etype[e]], 1);
  }
  __syncthreads();
  for (int i = tid; i < RR; i += 256) {
    int c = lh[i];
    lbase[i] = c ? atomicAdd(&cur[i], c) : 0;
    lcur[i] = 0;
  }
  __syncthreads();
  for (int i = tid; i < SCHUNK; i += 256) {
    int e = e0 + i;
    if (e < EE) {
      int et = etype[e];
      int s = lbase[et] + atomicAdd(&lcur[et], 1);
      perm[s] = e;
    }
  }
}

// --------- dst-CSR build: exclusive scan of deg (3 small kernels) ----------
__global__ __launch_bounds__(256) void k_dscan_a(const int* __restrict__ deg,
                                                 int* __restrict__ bsum) {
  int i = blockIdx.x * 256 + threadIdx.x;
  int v = (i < NN) ? deg[i] : 0;
#pragma unroll
  for (int d = 32; d; d >>= 1) v += __shfl_down(v, d, 64);
  __shared__ int ws4[4];
  if ((threadIdx.x & 63) == 0) ws4[threadIdx.x >> 6] = v;
  __syncthreads();
  if (threadIdx.x == 0) bsum[blockIdx.x] = ws4[0] + ws4[1] + ws4[2] + ws4[3];
}

__global__ __launch_bounds__(256) void k_dscan_b(int* __restrict__ bsum) {
  __shared__ int l[NSCAN];
  int tid = threadIdx.x;
  for (int i = tid; i < NSCAN; i += 256) l[i] = bsum[i];
  __syncthreads();
  if (tid == 0) {
    int s = 0;
    for (int i = 0; i < NSCAN; ++i) { int t = l[i]; l[i] = s; s += t; }
  }
  __syncthreads();
  for (int i = tid; i < NSCAN; i += 256) bsum[i] = l[i];
}

__global__ __launch_bounds__(256) void k_dscan_c(const int* __restrict__ deg,
                                                 const int* __restrict__ bsum,
                                                 int* __restrict__ row_ptr,
                                                 int* __restrict__ cur2) {
  int tid = threadIdx.x, b = blockIdx.x;
  int i = b * 256 + tid;
  int v = (i < NN) ? deg[i] : 0;
  int x = v;
#pragma unroll
  for (int d = 1; d < 64; d <<= 1) {
    int y = __shfl_up(x, d, 64);
    if ((tid & 63) >= d) x += y;
  }
  __shared__ int ws4[4];
  __shared__ int wo4[4];
  if ((tid & 63) == 63) ws4[tid >> 6] = x;
  __syncthreads();
  if (tid == 0) {
    int s = 0;
    for (int w2 = 0; w2 < 4; ++w2) { wo4[w2] = s; s += ws4[w2]; }
  }
  __syncthreads();
  int excl = x - v + wo4[tid >> 6] + bsum[b];
  if (i < NN) { row_ptr[i] = excl; cur2[i] = excl; }
  if (i == 0) row_ptr[NN] = EE;
}

// Kernel: scatter perm-positions into dst-CSR value list.
__global__ __launch_bounds__(256) void k_dlist(const int* __restrict__ perm,
                                               const int* __restrict__ dst,
                                               int* __restrict__ cur2,
                                               int* __restrict__ dlist) {
  for (int p = blockIdx.x * 256 + threadIdx.x; p < EE; p += gridDim.x * 256) {
    int e = perm[p];
    int d = dst[e];
    int pos = atomicAdd(&cur2[d], 1);
    dlist[pos] = p;
  }
}

// ---------------------------------------------------------------------------
// Shared 64x256 @ 256x256 MFMA core. lA: 64 rows x 512B bf16 in LDS,
// byte ^= ((row&7)<<4) swizzle. B fragments prefetched one kt ahead.
__device__ __forceinline__ void gemm64(const char* lA, const short* __restrict__ wpk,
                                       f32x4 acc[4][4], int wave, int lane) {
  int l15 = lane & 15, lg = lane >> 4;
  const short* bp = wpk + (size_t)wave * 4 * 4096 + (size_t)lane * 8;
  short8v b[4];
#pragma unroll
  for (int c = 0; c < 4; ++c) b[c] = *(const short8v*)(bp + c * 4096);
#pragma unroll
  for (int kt = 0; kt < 8; ++kt) {
    short8v bn[4];
    if (kt < 7) {
#pragma unroll
      for (int c = 0; c < 4; ++c) bn[c] = *(const short8v*)(bp + c * 4096 + (kt + 1) * 512);
    }
    short8v a[4];
#pragma unroll
    for (int m = 0; m < 4; ++m) {
      int row = m * 16 + l15;
      int off = (row * 512 + kt * 64 + lg * 16) ^ ((row & 7) << 4);
      a[m] = *(const short8v*)(lA + off);
    }
#pragma unroll
    for (int m = 0; m < 4; ++m)
#pragma unroll
      for (int c = 0; c < 4; ++c)
        acc[m][c] = __builtin_amdgcn_mfma_f32_16x16x32_bf16(a[m], b[c], acc[m][c], 0, 0, 0);
    if (kt < 7) {
#pragma unroll
      for (int c = 0; c < 4; ++c) b[c] = bn[c];
    }
  }
}

// Kernel 4: self-loop GEMM, overwrites d_out. B16: read pre-converted feat.
template <bool B16>
__global__ __launch_bounds__(256) void k_self_gemm(const float* __restrict__ in_feat,
                                                   const unsigned short* __restrict__ featb,
                                                   const short* __restrict__ spk,
                                                   float* __restrict__ out) {
  __shared__ short8v lAv[2048];              // 32 KiB
  char* lA = (char*)lAv;
  int n0 = blockIdx.x * 64;
  int tid = threadIdx.x;
  if (B16) {
    short8v sv[8];
#pragma unroll
    for (int u = 0; u < 8; ++u) {
      int idx = u * 256 + tid;
      int row = idx >> 5, q = idx & 31;
      int n = n0 + row;
      sv[u] = (n < NN) ? *(const short8v*)(featb + (size_t)n * 256 + q * 8)
                       : (short8v){0, 0, 0, 0, 0, 0, 0, 0};
    }
#pragma unroll
    for (int u = 0; u < 8; ++u) {
      int idx = u * 256 + tid;
      int row = idx >> 5, q = idx & 31;
      *(short8v*)(lA + ((row * 512 + q * 16) ^ ((row & 7) << 4))) = sv[u];
    }
  } else {
#pragma unroll
    for (int half = 0; half < 2; ++half) {
      float4 v[8];
#pragma unroll
      for (int u = 0; u < 8; ++u) {
        int it = half * 2048 + u * 256 + tid;
        int row = it >> 6, q = it & 63;
        int n = n0 + row;
        v[u] = (n < NN) ? ((const float4*)(in_feat + (size_t)n * 256))[q]
                        : make_float4(0.f, 0.f, 0.f, 0.f);
      }
#pragma unroll
      for (int u = 0; u < 8; ++u) {
        int it = half * 2048 + u * 256 + tid;
        int row = it >> 6, q = it & 63;
        ushort4 hh;
        hh.x = f2bf(v[u].x); hh.y = f2bf(v[u].y); hh.z = f2bf(v[u].z); hh.w = f2bf(v[u].w);
        *(ushort4*)(lA + ((row * 512 + q * 8) ^ ((row & 7) << 4))) = hh;
      }
    }
  }
  __syncthreads();
  f32x4 acc[4][4];
#pragma unroll
  for (int m = 0; m < 4; ++m)
#pragma unroll
    for (int c = 0; c < 4; ++c) acc[m][c] = (f32x4){0.f, 0.f, 0.f, 0.f};
  int wave = tid >> 6, lane = tid & 63;
  gemm64(lA, spk, acc, wave, lane);
  int l15 = lane & 15, lg = lane >> 4;
#pragma unroll
  for (int m = 0; m < 4; ++m)
#pragma unroll
    for (int j = 0; j < 4; ++j) {
      int n = n0 + m * 16 + lg * 4 + j;
      if (n < NN) {
        float* op = out + (size_t)n * 256 + wave * 64 + l15;
#pragma unroll
        for (int c = 0; c < 4; ++c) op[c * 16] = acc[m][c][j];
      }
    }
}

// Kernel 5: per-relation edge GEMM. MODE 0: f32 feat + atomic epilogue.
// MODE 1: bf16 feat + atomic epilogue. MODE 2: bf16 feat + msg-buffer store.
template <int MODE>
__global__ __launch_bounds__(256) void k_edge_gemm(const float* __restrict__ in_feat,
                                                   const unsigned short* __restrict__ featb,
                                                   const short* __restrict__ wpk,
                                                   const int* __restrict__ src,
                                                   const int* __restrict__ dst,
                                                   const int* __restrict__ deg,
                                                   const int* __restrict__ perm,
                                                   const int4* __restrict__ tdesc,
                                                   float* __restrict__ out,
                                                   unsigned short* __restrict__ msg) {
  __shared__ short8v lAv[2048];              // 32 KiB
  __shared__ int lsrc[64];
  __shared__ int ldst[64];
  __shared__ float linv[64];
  char* lA = (char*)lAv;
  // XCD swizzle: XCD k gets contiguous tile range -> wpk slice fits 4MB L2.
  int bid = blockIdx.x;
  int tile = (bid & 7) * (MAXTILES / 8) + (bid >> 3);
  int4 d = tdesc[tile];
  int rows = d.z;
  if (rows <= 0) return;
  int r = d.x, rs = d.y;
  int tid = threadIdx.x;
  if (tid < 64) {
    if (tid < rows) {
      int e = perm[rs + tid];
      lsrc[tid] = src[e];
      int dd = dst[e];
      ldst[tid] = dd;
      linv[tid] = 1.0f / (float)max(deg[dd], 1);
    } else {
      lsrc[tid] = -1; ldst[tid] = -1; linv[tid] = 0.f;
    }
  }
  __syncthreads();
  if (MODE >= 1) {
    short8v sv[8];
#pragma unroll
    for (int u = 0; u < 8; ++u) {
      int idx = u * 256 + tid;
      int row = idx >> 5, q = idx & 31;
      int s = lsrc[row];
      sv[u] = (s >= 0) ? *(const short8v*)(featb + (size_t)s * 256 + q * 8)
                       : (short8v){0, 0, 0, 0, 0, 0, 0, 0};
    }
#pragma unroll
    for (int u = 0; u < 8; ++u) {
      int idx = u * 256 + tid;
      int row = idx >> 5, q = idx & 31;
      *(short8v*)(lA + ((row * 512 + q * 16) ^ ((row & 7) << 4))) = sv[u];
    }
  } else {
#pragma unroll
    for (int half = 0; half < 2; ++half) {
      float4 v[8];
#pragma unroll
      for (int u = 0; u < 8; ++u) {
        int it = half * 2048 + u * 256 + tid;
        int row = it >> 6, q = it & 63;
        int s = lsrc[row];
        v[u] = (s >= 0) ? ((const float4*)(in_feat + (size_t)s * 256))[q]
                        : make_float4(0.f, 0.f, 0.f, 0.f);
      }
#pragma unroll
      for (int u = 0; u < 8; ++u) {
        int it = half * 2048 + u * 256 + tid;
        int row = it >> 6, q = it & 63;
        ushort4 hh;
        hh.x = f2bf(v[u].x); hh.y = f2bf(v[u].y); hh.z = f2bf(v[u].z); hh.w = f2bf(v[u].w);
        *(ushort4*)(lA + ((row * 512 + q * 8) ^ ((row & 7) << 4))) = hh;
      }
    }
  }
  __syncthreads();
  f32x4 acc[4][4];
#pragma unroll
  for (int m = 0; m < 4; ++m)
#pragma unroll
    for (int c = 0; c < 4; ++c) acc[m][c] = (f32x4){0.f, 0.f, 0.f, 0.f};
  int wave = tid >> 6, lane = tid & 63;
  gemm64(lA, wpk + (size_t)r * 65536, acc, wave, lane);
  int l15 = lane & 15, lg = lane >> 4;
  if (MODE == 2) {
    // Repack scaled bf16 messages via LDS, then 16B-coalesced stores to msg.
    __syncthreads();                       // all waves done reading lA
#pragma unroll
    for (int m = 0; m < 4; ++m)
#pragma unroll
      for (int j = 0; j < 4; ++j) {
        int row = m * 16 + lg * 4 + j;
        float inv = linv[row];
        int rb = row * 512, sw = (row & 7) << 4;
#pragma unroll
        for (int c = 0; c < 4; ++c) {
          int col = wave * 64 + c * 16 + l15;
          *(unsigned short*)(lA + ((rb + col * 2) ^ sw)) = f2bf(acc[m][c][j] * inv);
        }
      }
    __syncthreads();
#pragma unroll
    for (int u = 0; u < 8; ++u) {
      int idx = u * 256 + tid;
      int row = idx >> 5, q = idx & 31;
      if (row < rows) {
        short8v vv = *(const short8v*)(lA + ((row * 512 + q * 16) ^ ((row & 7) << 4)));
        *(short8v*)(msg + (size_t)(rs + row) * 256 + q * 8) = vv;
      }
    }
  } else {
#pragma unroll
    for (int m = 0; m < 4; ++m)
#pragma unroll
      for (int j = 0; j < 4; ++j) {
        int row = m * 16 + lg * 4 + j;
        int dd = ldst[row];
        if (dd >= 0) {
          float inv = linv[row];
          float* op = out + (size_t)dd * 256 + wave * 64 + l15;
#pragma unroll
          for (int c = 0; c < 4; ++c) unsafeAtomicAdd(op + c * 16, acc[m][c][j] * inv);
        }
      }
  }
}

// Kernel 6: per-dst aggregation: out[d] += sum of msg rows (already /deg).
__global__ __launch_bounds__(256) void k_aggregate(const unsigned short* __restrict__ msg,
                                                   const int* __restrict__ row_ptr,
                                                   const int* __restrict__ dlist,
                                                   float* __restrict__ out) {
  int wgid = blockIdx.x * 4 + (threadIdx.x >> 6);
  int lane = threadIdx.x & 63;
  int nw = gridDim.x * 4;
  for (int d = wgid; d < NN; d += nw) {
    int lo = row_ptr[d], hi = row_ptr[d + 1];
    if (lo >= hi) continue;
    float a0 = 0.f, a1 = 0.f, a2 = 0.f, a3 = 0.f;
    for (int q0 = lo; q0 < hi; q0 += 8) {
      int qm = min(8, hi - q0);
      int pv = (q0 + (lane & 7) < hi) ? dlist[q0 + (lane & 7)] : 0;
      for (int j = 0; j < qm; ++j) {
        int p = __shfl(pv, j, 8);
        ushort4 mv = *(const ushort4*)(msg + (size_t)p * 256 + lane * 4);
        a0 += bf2f(mv.x); a1 += bf2f(mv.y); a2 += bf2f(mv.z); a3 += bf2f(mv.w);
      }
    }
    float4* op = (float4*)(out + (size_t)d * 256 + lane * 4);
    float4 o = *op;
    o.x += a0; o.y += a1; o.z += a2; o.w += a3;
    *op = o;
  }
}

// ---------------------------------------------------------------------------
extern "C" void kernel_launch(void* const* d_in, const int* in_sizes, int n_in,
                              void* d_out, int out_size, void* d_ws, size_t ws_size,
                              hipStream_t stream) {
  const float* in_feat = (const float*)d_in[0];
  const float* basis   = (const float*)d_in[1];
  const float* coef    = (const float*)d_in[2];
  const float* slw     = (const float*)d_in[3];
  const int*   src     = (const int*)d_in[4];
  const int*   dst     = (const int*)d_in[5];
  const int*   etype   = (const int*)d_in[6];
  float* out = (float*)d_out;

  char* base = (char*)d_ws;
  char* w = base;
  auto alloc = [&](size_t bytes) {
    char* p = w;
    w += (bytes + 255) & ~(size_t)255;
    return p;
  };
  // base group (tier C)
  short* wpk  = (short*)alloc((size_t)RR * 65536 * 2);   // 26.2 MB
  short* spk  = (short*)alloc(65536 * 2);
  int*   perm = (int*)alloc((size_t)EE * 4);
  int*   deg  = (int*)alloc((size_t)NN * 4);
  int*   hist = (int*)alloc(RR * 4);
  int*   cur  = (int*)alloc(RR * 4);
  int4*  tdesc = (int4*)alloc((size_t)MAXTILES * 16);
  int*   bsum = (int*)alloc(NSCAN * 4);
  // tier B adds bf16 feat
  unsigned short* featb = (unsigned short*)alloc((size_t)NN * 256 * 2);  // 51.2 MB
  size_t need_b = (size_t)(w - base);
  // tier A adds dst-CSR + msg buffer
  int* row_ptr = (int*)alloc((size_t)(NN + 1) * 4);
  int* cur2    = (int*)alloc((size_t)NN * 4);
  int* dlist   = (int*)alloc((size_t)EE * 4);
  unsigned short* msg = (unsigned short*)alloc((size_t)EE * 256 * 2);    // 204.8 MB
  size_t need_a = (size_t)(w - base);

  bool tierA = ws_size >= need_a;
  bool tierB = ws_size >= need_b;

  hipMemsetAsync(hist, 0, RR * 4, stream);
  hipMemsetAsync(deg, 0, (size_t)NN * 4, stream);

  k_wgen<<<800, 256, 0, stream>>>(basis, coef, wpk);
  k_slwpk<<<32, 256, 0, stream>>>(slw, spk);
  k_hist<<<256, 256, 0, stream>>>(etype, dst, hist, deg);
  k_scan<<<1, 256, 0, stream>>>(hist, cur, tdesc);
  k_scatter<<<(EE + SCHUNK - 1) / SCHUNK, 256, 0, stream>>>(etype, cur, perm);
  if (tierA || tierB) k_feat<<<2048, 256, 0, stream>>>(in_feat, featb);

  if (tierA) {
    k_dscan_a<<<NSCAN, 256, 0, stream>>>(deg, bsum);
    k_dscan_b<<<1, 256, 0, stream>>>(bsum);
    k_dscan_c<<<NSCAN, 256, 0, stream>>>(deg, bsum, row_ptr, cur2);
    k_dlist<<<512, 256, 0, stream>>>(perm, dst, cur2, dlist);
    k_self_gemm<true><<<(NN + 63) / 64, 256, 0, stream>>>(in_feat, featb, spk, out);
    k_edge_gemm<2><<<MAXTILES, 256, 0, stream>>>(in_feat, featb, wpk, src, dst, deg,
                                                 perm, tdesc, out, msg);
    k_aggregate<<<1024, 256, 0, stream>>>(msg, row_ptr, dlist, out);
  } else if (tierB) {
    k_self_gemm<true><<<(NN + 63) / 64, 256, 0, stream>>>(in_feat, featb, spk, out);
    k_edge_gemm<1><<<MAXTILES, 256, 0, stream>>>(in_feat, featb, wpk, src, dst, deg,
                                                 perm, tdesc, out, nullptr);
  } else {
    k_self_gemm<false><<<(NN + 63) / 64, 256, 0, stream>>>(in_feat, nullptr, spk, out);
    k_edge_gemm<0><<<MAXTILES, 256, 0, stream>>>(in_feat, nullptr, wpk, src, dst, deg,
                                                 perm, tdesc, out, nullptr);
  }
}